// Round 1
// baseline (76.877 us; speedup 1.0000x reference)
//
#include <hip/hip_runtime.h>
#include <stdint.h>

#define FP8_MAX 448.0f

typedef __attribute__((ext_vector_type(4))) float f32x4;
typedef long long ll;

// ---------------------------------------------------------------------------
// scale handling, replicating flax fp8_ops.compute_scale:
//   sf = fp8_max/amax; sf = amax>0 ? sf : 1/scale; sf = isfinite(amax)? sf : 1/scale
//   new_scale = 1/sf   (we keep sf = the multiplier applied before fp8 cast)
// ---------------------------------------------------------------------------
__device__ __forceinline__ float scale_factor(float amax, float prev_scale) {
    float sf = FP8_MAX / amax;
    if (!(amax > 0.0f) || !isfinite(amax)) sf = 1.0f / prev_scale;
    return sf;
}

__device__ __forceinline__ unsigned pack4_fp8(float a, float b, float c, float d) {
    int v = __builtin_amdgcn_cvt_pk_fp8_f32(a, b, 0, false);
    v = __builtin_amdgcn_cvt_pk_fp8_f32(c, d, v, true);
    return (unsigned)v;
}

__device__ __forceinline__ float qclamp(float x, float sf) {
    return fminf(fmaxf(x * sf, -FP8_MAX), FP8_MAX);
}

// ---------------------------------------------------------------------------
// amax over n4 float4's (abs max), result as float bits via atomicMax(uint)
// ---------------------------------------------------------------------------
__global__ void amax_kernel(const float* __restrict__ in, unsigned n4,
                            unsigned* __restrict__ out) {
    const f32x4* p = (const f32x4*)in;
    float m = 0.0f;
    unsigned stride = gridDim.x * blockDim.x;
    for (unsigned i = blockIdx.x * blockDim.x + threadIdx.x; i < n4; i += stride) {
        f32x4 v = p[i];
        float a0 = fmaxf(__builtin_fabsf(v.x), __builtin_fabsf(v.y));
        float a1 = fmaxf(__builtin_fabsf(v.z), __builtin_fabsf(v.w));
        m = fmaxf(m, fmaxf(a0, a1));
    }
    #pragma unroll
    for (int off = 32; off; off >>= 1)
        m = fmaxf(m, __shfl_down(m, off, 64));
    __shared__ float sm[4];
    int lane = threadIdx.x & 63;
    int w = threadIdx.x >> 6;
    if (lane == 0) sm[w] = m;
    __syncthreads();
    if (threadIdx.x == 0) {
        float mm = sm[0];
        int nw = blockDim.x >> 6;
        for (int i = 1; i < nw; ++i) mm = fmaxf(mm, sm[i]);
        atomicMax(out, __float_as_uint(mm));
    }
}

// ---------------------------------------------------------------------------
// quantize k [256,256] (d-major, f minor) into MFMA B-fragment-packed layout:
//   pack[kstep*1024 + ntile*64 + lane] = 8 fp8 bytes:
//     byte j: col = ntile*16 + (lane&15), k = kstep*32 + (lane>>4)*8 + j
// ---------------------------------------------------------------------------
__global__ void pack_k_kernel(const float* __restrict__ kin,
                              const unsigned* __restrict__ amax_bits,
                              const float* __restrict__ prev_scale,
                              ll* __restrict__ pack) {
    float amax = __uint_as_float(amax_bits[1]);
    float sf = scale_factor(amax, prev_scale[0]);
    int t = blockIdx.x * blockDim.x + threadIdx.x;  // 0..8191
    if (t >= 8192) return;
    int lane = t & 63;
    int nt = (t >> 6) & 15;
    int kstep = t >> 10;
    int col = nt * 16 + (lane & 15);
    int k0 = kstep * 32 + (lane >> 4) * 8;
    float v[8];
    #pragma unroll
    for (int j = 0; j < 8; ++j)
        v[j] = qclamp(kin[(k0 + j) * 256 + col], sf);
    unsigned lo = pack4_fp8(v[0], v[1], v[2], v[3]);
    unsigned hi = pack4_fp8(v[4], v[5], v[6], v[7]);
    pack[t] = (ll)lo | ((ll)hi << 32);
}

// ---------------------------------------------------------------------------
// GEMM: C[M,256] = qdq(x)[M,256] * qdq(k)[256,256], fp8 MFMA, epilogue scale.
// Block: 256 threads = 4 waves, BM=64 (16 rows/wave), full N=256 per wave
// (16 N-tiles of 16). K=256 in 8 steps of 32.
// ---------------------------------------------------------------------------
__global__ __launch_bounds__(256) void gemm_kernel(
    const float* __restrict__ x, const ll* __restrict__ Bpack,
    const unsigned* __restrict__ amax_bits,
    const float* __restrict__ ps_x, const float* __restrict__ ps_k,
    float* __restrict__ C) {
    float sf_x = scale_factor(__uint_as_float(amax_bits[0]), ps_x[0]);
    float sf_k = scale_factor(__uint_as_float(amax_bits[1]), ps_k[0]);
    float outscale = (1.0f / sf_x) * (1.0f / sf_k);

    int w = threadIdx.x >> 6;
    int lane = threadIdx.x & 63;
    int kg = lane >> 4;                       // 0..3
    int row = blockIdx.x * 64 + w * 16 + (lane & 15);
    const float* xp = x + (size_t)row * 256 + kg * 8;

    f32x4 acc[16];
    #pragma unroll
    for (int i = 0; i < 16; ++i) acc[i] = (f32x4){0.f, 0.f, 0.f, 0.f};

    #pragma unroll
    for (int ks = 0; ks < 8; ++ks) {
        f32x4 a0 = *(const f32x4*)(xp + ks * 32);
        f32x4 a1 = *(const f32x4*)(xp + ks * 32 + 4);
        unsigned lo = pack4_fp8(qclamp(a0.x, sf_x), qclamp(a0.y, sf_x),
                                qclamp(a0.z, sf_x), qclamp(a0.w, sf_x));
        unsigned hi = pack4_fp8(qclamp(a1.x, sf_x), qclamp(a1.y, sf_x),
                                qclamp(a1.z, sf_x), qclamp(a1.w, sf_x));
        ll A = (ll)lo | ((ll)hi << 32);
        const ll* bp = Bpack + ks * 1024 + lane;
        #pragma unroll
        for (int nt = 0; nt < 16; ++nt) {
            ll Bf = bp[nt * 64];
            acc[nt] = __builtin_amdgcn_mfma_f32_16x16x32_fp8_fp8(A, Bf, acc[nt], 0, 0, 0);
        }
    }

    // C/D layout: col = lane&15, row = (lane>>4)*4 + r   [m89, dtype-independent]
    int crow = blockIdx.x * 64 + w * 16 + kg * 4;
    int ccol = lane & 15;
    #pragma unroll
    for (int nt = 0; nt < 16; ++nt) {
        #pragma unroll
        for (int r = 0; r < 4; ++r) {
            C[(size_t)(crow + r) * 256 + nt * 16 + ccol] = acc[nt][r] * outscale;
        }
    }
}

// ---------------------------------------------------------------------------
extern "C" void kernel_launch(void* const* d_in, const int* in_sizes, int n_in,
                              void* d_out, int out_size, void* d_ws, size_t ws_size,
                              hipStream_t stream) {
    const float* x = (const float*)d_in[0];             // [8,8192,256] f32
    const float* k = (const float*)d_in[1];             // [256,256] f32
    const float* input_scale = (const float*)d_in[2];   // [1]
    const float* kernel_scale = (const float*)d_in[3];  // [1]
    float* out = (float*)d_out;

    unsigned* amax_bits = (unsigned*)d_ws;              // [0]=amax_x, [1]=amax_k
    ll* pack = (ll*)((char*)d_ws + 256);                // 64 KiB packed fp8 B

    int nx = in_sizes[0];                               // 16,777,216
    int nk = in_sizes[1];                               // 65,536
    int M = nx / 256;                                   // 65,536

    hipMemsetAsync(d_ws, 0, 16, stream);
    amax_kernel<<<2048, 256, 0, stream>>>(x, (unsigned)(nx / 4), amax_bits + 0);
    amax_kernel<<<64, 256, 0, stream>>>(k, (unsigned)(nk / 4), amax_bits + 1);
    pack_k_kernel<<<32, 256, 0, stream>>>(k, amax_bits, kernel_scale, pack);
    gemm_kernel<<<M / 64, 256, 0, stream>>>(x, pack, amax_bits, input_scale,
                                            kernel_scale, out);
}